// Round 20
// baseline (129.590 us; speedup 1.0000x reference)
//
#include <hip/hip_runtime.h>
#include <hip/hip_fp16.h>

#define H_  192
#define W_  192
#define HW  36864
#define B_  4

typedef __attribute__((ext_vector_type(8))) short short8;
typedef __attribute__((ext_vector_type(4))) float f32x4;
typedef __attribute__((ext_vector_type(4))) unsigned int u32x4;
typedef unsigned short ushort_t;
typedef unsigned int uint_t;

__device__ __forceinline__ ushort_t f2h(float v) {
    __half h = __float2half(v);
    ushort_t s;
    __builtin_memcpy(&s, &h, 2);
    return s;
}
__device__ __forceinline__ float h2f(ushort_t s) {
    __half h;
    __builtin_memcpy(&h, &s, 2);
    return __half2float(h);
}
__device__ __forceinline__ __half2 u2h2(uint_t u) {
    __half2 h;
    __builtin_memcpy(&h, &u, 4);
    return h;
}
__device__ __forceinline__ uint_t h22u(__half2 h) {
    uint_t u;
    __builtin_memcpy(&u, &h, 4);
    return u;
}
__device__ __forceinline__ short8 zero8() {
    u32x4 z = {0u, 0u, 0u, 0u};
    return __builtin_bit_cast(short8, z);
}

// async copy: per-lane global src -> LDS[wave_base + lane*16]
__device__ __forceinline__ void glds16(const ushort_t* src, void* lds_base) {
    __builtin_amdgcn_global_load_lds(
        (const __attribute__((address_space(1))) void*)src,
        (__attribute__((address_space(3))) void*)lds_base, 16, 0, 0);
}

// ============ KT+K0: transpose x -> fp16 NHWC, plus weight prep (merged) ============
__global__ __launch_bounds__(256) void prep_transpose_kernel(
    const float* __restrict__ x, ushort_t* __restrict__ x_t,
    const float* __restrict__ dw, const float* __restrict__ db,
    const float* __restrict__ g, const float* __restrict__ be,
    const float* __restrict__ mu, const float* __restrict__ var,
    const float* __restrict__ ow,
    ushort_t* __restrict__ w_bf, ushort_t* __restrict__ w_off,
    float* __restrict__ scale, float* __restrict__ shift) {
    __shared__ uint_t tlds[256 * 33];
    int tid = threadIdx.x;

    // ---- prep part (blocks 0..215 carry weight work) ----
    int idx = blockIdx.x * 256 + tid;
    if (idx < 36864) {
        int tap = idx >> 12, o = (idx >> 6) & 63, c = idx & 63;
        w_bf[idx] = f2h(dw[(o * 64 + c) * 9 + tap]);
    }
    int idx2 = idx - 36864;
    if (idx2 >= 0 && idx2 < 18432) {
        int tap = idx2 >> 11, o = (idx2 >> 6) & 31, c = idx2 & 63;
        w_off[idx2] = (o < 18) ? f2h(ow[(o * 64 + c) * 9 + tap]) : (ushort_t)0;
    }
    if (idx < 64) {
        float s = g[idx] * rsqrtf(var[idx] + 1e-5f);
        scale[idx] = s;
        shift[idx] = (db[idx] - mu[idx]) * s + be[idx];
    }

    // ---- transpose part ----
    int b = blockIdx.x / 144;
    int p0 = (blockIdx.x % 144) * 256;
    ushort_t* ts = (ushort_t*)tlds;
    for (int c = 0; c < 64; ++c) {
        float v = x[((size_t)(b * 64 + c)) * HW + p0 + tid];
        ts[tid * 66 + c] = f2h(v);
    }
    __syncthreads();
#pragma unroll
    for (int j = 0; j < 8; ++j) {
        int chunk = j * 256 + tid;
        int pl = chunk >> 3, s = chunk & 7;
        int bd = pl * 33 + s * 4;
        u32x4 v = {tlds[bd], tlds[bd + 1], tlds[bd + 2], tlds[bd + 3]};
        ((u32x4*)x_t)[(size_t)(b * HW + p0) * 8 + chunk] = v;
    }
}

// ============ helpers for fused deform ============
__device__ __forceinline__ u32x4 prd(const ushort_t* patch, int q, int slot) {
    return *(const u32x4*)((const char*)patch + q * 128 + ((slot ^ (q & 7)) << 4));
}

__device__ __forceinline__ bool corner_setup2(float ody, float odx,
                                              int ybase, int xbase, int ytop, int xleft,
                                              int* q, int* g, float* w) {
    float py = (float)ybase + ody;
    float px = (float)xbase + odx;
    float fy = floorf(py), fx = floorf(px);
    int y0 = (int)fy, x0 = (int)fx;
    float wy = py - fy, wx = px - fx;
    int y0c = min(max(y0, 0), H_ - 1), y1c = min(max(y0 + 1, 0), H_ - 1);
    int x0c = min(max(x0, 0), W_ - 1), x1c = min(max(x0 + 1, 0), W_ - 1);
    float vy0 = (y0 >= 0 && y0 < H_) ? 1.f : 0.f;
    float vy1 = (y0 + 1 >= 0 && y0 + 1 < H_) ? 1.f : 0.f;
    float vx0 = (x0 >= 0 && x0 < W_) ? 1.f : 0.f;
    float vx1 = (x0 + 1 >= 0 && x0 + 1 < W_) ? 1.f : 0.f;
    w[0] = (1.f - wy) * (1.f - wx) * vy0 * vx0;
    w[1] = (1.f - wy) * wx * vy0 * vx1;
    w[2] = wy * (1.f - wx) * vy1 * vx0;
    w[3] = wy * wx * vy1 * vx1;
    g[0] = (y0c * W_ + x0c) * 64; g[1] = (y0c * W_ + x1c) * 64;
    g[2] = (y1c * W_ + x0c) * 64; g[3] = (y1c * W_ + x1c) * 64;
    int iy0 = y0c - ytop, iy1 = y1c - ytop;
    int ix0 = x0c - xleft, ix1 = x1c - xleft;
    q[0] = iy0 * 56 + ix0; q[1] = iy0 * 56 + ix1;
    q[2] = iy1 * 56 + ix0; q[3] = iy1 * 56 + ix1;
    return ((unsigned)iy0 <= 11u) & ((unsigned)iy1 <= 11u) &
           ((unsigned)ix0 <= 55u) & ((unsigned)ix1 <= 55u);
}

__device__ __forceinline__ short8 interp_f16(const u32x4* buf, const __half2* w2) {
    short8 r;
#pragma unroll
    for (int q = 0; q < 4; ++q) {
        __half2 acc = __hmul2(u2h2(buf[0][q]), w2[0]);
        acc = __hfma2(u2h2(buf[1][q]), w2[1], acc);
        acc = __hfma2(u2h2(buf[2][q]), w2[2], acc);
        acc = __hfma2(u2h2(buf[3][q]), w2[3], acc);
        ((uint_t*)&r)[q] = h22u(acc);
    }
    return r;
}

// ============ K2: fused offset-conv + deformable conv (+ optional sync-free pooled partials).
// Block = 6 rows x 48 cols = 288 positions, 576 threads (9 waves); patch 12x56 px = 86 KB. ============
template <bool POOL>
__global__ __launch_bounds__(576, 2) void deform_fused_kernel(
    const ushort_t* __restrict__ x_t, const ushort_t* __restrict__ w_off,
    const float* __restrict__ ob, const ushort_t* __restrict__ w_bf,
    const float* __restrict__ scale_g, const float* __restrict__ shift_g,
    ushort_t* __restrict__ h16, float* __restrict__ partial) {
    __shared__ __align__(16) ushort_t patch[672 * 64];   // 86016 B

    int tid = threadIdx.x;
    int lane = tid & 63, w = tid >> 6;
    int tile = (blockIdx.x & 7) * 64 + (blockIdx.x >> 3);   // XCD-bijective
    int b = tile / 128;
    int rem = tile % 128;
    int y0 = (rem >> 2) * 6;
    int x0 = (rem & 3) * 48;
    int ytop = y0 - 3, xleft = x0 - 4;

    int ln = lane & 15, kg = lane >> 4;
    int locA = w * 32 + ln, locB = locA + 16;
    int rowA = locA / 48, colA = locA - rowA * 48;
    int rowB = locB / 48, colB = locB - rowB * 48;
    int yA = y0 + rowA, xA = x0 + colA;
    int yB = y0 + rowB, xB = x0 + colB;
    const ushort_t* xt_b = x_t + (size_t)b * (HW * 64);

    // ---- stage halo patch ----
    {
        char* pbase = (char*)patch;
#pragma unroll
        for (int t = 0; t < 10; ++t) {
            if (t * 576 + w * 64 < 5376) {
                int g = t * 576 + tid;
                int q = g >> 3, sp = g & 7;
                int i = q / 56, j = q - i * 56;
                int pr = min(max(ytop + i, 0), H_ - 1);
                int pc = min(max(xleft + j, 0), W_ - 1);
                int s = sp ^ (q & 7);
                glds16(xt_b + (pr * W_ + pc) * 64 + s * 8,
                       pbase + (size_t)(t * 576 + w * 64) * 16);
            }
        }
    }
    asm volatile("s_waitcnt vmcnt(0)" ::: "memory");
    __syncthreads();

    // ---- phase 0: offset conv ----
    f32x4 ao[2][2];
#pragma unroll
    for (int i = 0; i < 2; ++i)
#pragma unroll
        for (int j = 0; j < 2; ++j) ao[i][j] = (f32x4){0.f, 0.f, 0.f, 0.f};

    for (int tap = 0; tap < 9; ++tap) {
        int ti = tap / 3 - 1, tj = tap % 3 - 1;
        bool vA = ((unsigned)(yA + ti) < (unsigned)H_) && ((unsigned)(xA + tj) < (unsigned)W_);
        bool vB = ((unsigned)(yB + ti) < (unsigned)H_) && ((unsigned)(xB + tj) < (unsigned)W_);
        int qA = (rowA + 3 + ti) * 56 + (colA + 4 + tj);
        int qB = (rowB + 3 + ti) * 56 + (colB + 4 + tj);
        const ushort_t* wt = w_off + tap * 2048;
#pragma unroll
        for (int ks = 0; ks < 2; ++ks) {
            int ch = ks * 32 + kg * 8;
            int slot = kg + ks * 4;
            short8 a0 = *(const short8*)(wt + ln * 64 + ch);
            short8 a1 = *(const short8*)(wt + (16 + ln) * 64 + ch);
            short8 bA = vA ? __builtin_bit_cast(short8, prd(patch, qA, slot)) : zero8();
            short8 bB = vB ? __builtin_bit_cast(short8, prd(patch, qB, slot)) : zero8();
            ao[0][0] = __builtin_amdgcn_mfma_f32_16x16x32_f16(a0, bA, ao[0][0], 0, 0, 0);
            ao[0][1] = __builtin_amdgcn_mfma_f32_16x16x32_f16(a0, bB, ao[0][1], 0, 0, 0);
            ao[1][0] = __builtin_amdgcn_mfma_f32_16x16x32_f16(a1, bA, ao[1][0], 0, 0, 0);
            ao[1][1] = __builtin_amdgcn_mfma_f32_16x16x32_f16(a1, bB, ao[1][1], 0, 0, 0);
        }
    }

    // ---- redistribute offsets via intra-wave shuffles ----
    float offA[18], offB[18];
#pragma unroll
    for (int m = 0; m < 18; ++m) {
        int src = (((m >> 2) & 3) << 4) | ln;
        float bias = ob[m];
        offA[m] = __shfl(ao[m >> 4][0][m & 3], src, 64) + bias;
        offB[m] = __shfl(ao[m >> 4][1][m & 3], src, 64) + bias;
    }

    // ---- main: deformable conv ----
    f32x4 acc[4][2];
#pragma unroll
    for (int mt = 0; mt < 4; ++mt)
#pragma unroll
        for (int nt = 0; nt < 2; ++nt) acc[mt][nt] = (f32x4){0.f, 0.f, 0.f, 0.f};

#pragma unroll
    for (int tap = 0; tap < 9; ++tap) {
        int ti = tap / 3 - 1, tj = tap % 3 - 1;
        int qA[4], qB[4], gA[4], gB[4];
        float wA[4], wB[4];
        bool inA = corner_setup2(offA[2 * tap], offA[2 * tap + 1],
                                 yA + ti, xA + tj, ytop, xleft, qA, gA, wA);
        bool inB = corner_setup2(offB[2 * tap], offB[2 * tap + 1],
                                 yB + ti, xB + tj, ytop, xleft, qB, gB, wB);
        __half2 wA2[4], wB2[4];
#pragma unroll
        for (int c = 0; c < 4; ++c) {
            wA2[c] = __float2half2_rn(wA[c]);
            wB2[c] = __float2half2_rn(wB[c]);
        }
        const ushort_t* wt = w_bf + tap * 4096;
#pragma unroll
        for (int ks = 0; ks < 2; ++ks) {
            int ch = ks * 32 + kg * 8;
            int slot = kg + ks * 4;
            u32x4 cA[4], cB[4];
            if (__builtin_expect(inA, 1)) {
#pragma unroll
                for (int c = 0; c < 4; ++c) cA[c] = prd(patch, qA[c], slot);
            } else {
#pragma unroll
                for (int c = 0; c < 4; ++c) cA[c] = *(const u32x4*)(xt_b + gA[c] + ch);
            }
            if (__builtin_expect(inB, 1)) {
#pragma unroll
                for (int c = 0; c < 4; ++c) cB[c] = prd(patch, qB[c], slot);
            } else {
#pragma unroll
                for (int c = 0; c < 4; ++c) cB[c] = *(const u32x4*)(xt_b + gB[c] + ch);
            }
            short8 fA = interp_f16(cA, wA2);
            short8 fB = interp_f16(cB, wB2);
            short8 a0 = *(const short8*)(wt + (0 + ln) * 64 + ch);
            short8 a1 = *(const short8*)(wt + (16 + ln) * 64 + ch);
            short8 a2 = *(const short8*)(wt + (32 + ln) * 64 + ch);
            short8 a3 = *(const short8*)(wt + (48 + ln) * 64 + ch);
            acc[0][0] = __builtin_amdgcn_mfma_f32_16x16x32_f16(a0, fA, acc[0][0], 0, 0, 0);
            acc[0][1] = __builtin_amdgcn_mfma_f32_16x16x32_f16(a0, fB, acc[0][1], 0, 0, 0);
            acc[1][0] = __builtin_amdgcn_mfma_f32_16x16x32_f16(a1, fA, acc[1][0], 0, 0, 0);
            acc[1][1] = __builtin_amdgcn_mfma_f32_16x16x32_f16(a1, fB, acc[1][1], 0, 0, 0);
            acc[2][0] = __builtin_amdgcn_mfma_f32_16x16x32_f16(a2, fA, acc[2][0], 0, 0, 0);
            acc[2][1] = __builtin_amdgcn_mfma_f32_16x16x32_f16(a2, fB, acc[2][1], 0, 0, 0);
            acc[3][0] = __builtin_amdgcn_mfma_f32_16x16x32_f16(a3, fA, acc[3][0], 0, 0, 0);
            acc[3][1] = __builtin_amdgcn_mfma_f32_16x16x32_f16(a3, fB, acc[3][1], 0, 0, 0);
        }
    }

    // ---- epilogue: BN affine + fp16 store ----
    int pixA = yA * W_ + xA;
    int pixB = yB * W_ + xB;
    float vsum[4][4];
#pragma unroll
    for (int mt = 0; mt < 4; ++mt) {
#pragma unroll
        for (int r = 0; r < 4; ++r) {
            int m = mt * 16 + kg * 4 + r;
            float sc = scale_g[m], sh = shift_g[m];
            size_t obase = (size_t)(b * 64 + m) * HW;
            float v0 = acc[mt][0][r] * sc + sh;
            float v1 = acc[mt][1][r] * sc + sh;
            h16[obase + pixA] = f2h(v0);
            h16[obase + pixB] = f2h(v1);
            vsum[mt][r] = v0 + v1;
        }
    }

    // ---- sync-free per-wave pooled partials ----
    if constexpr (POOL) {
        float vs[4][4];
#pragma unroll
        for (int mt = 0; mt < 4; ++mt)
#pragma unroll
            for (int r = 0; r < 4; ++r) {
                float v = vsum[mt][r];
                v += __shfl_xor(v, 1, 16);
                v += __shfl_xor(v, 2, 16);
                v += __shfl_xor(v, 4, 16);
                v += __shfl_xor(v, 8, 16);
                vs[mt][r] = v;
            }
        int rl = lane & 3, ml = (lane >> 2) & 3;
        float val = vs[0][0];
#pragma unroll
        for (int mt = 0; mt < 4; ++mt)
#pragma unroll
            for (int r = 0; r < 4; ++r)
                val = (ml == mt && rl == r) ? vs[mt][r] : val;
        int c = kg * 4 + rl + 16 * ml;   // bijective lane->channel
        partial[(size_t)(tile * 9 + w) * 64 + c] = val;
    }
}

// ============ KR: coalesced reduce partials -> pooled mean (grid=4) ============
__global__ __launch_bounds__(256) void reduce_kernel(const float* __restrict__ partial,
                                                     float* __restrict__ pooled) {
    __shared__ float red[256];
    int b = blockIdx.x, t = threadIdx.x, c = t & 63, qq = t >> 6;
    float s = 0.f;
    for (int row = qq * 288; row < qq * 288 + 288; ++row)
        s += partial[(size_t)(b * 1152 + row) * 64 + c];
    red[t] = s;
    __syncthreads();
    if (t < 64)
        pooled[b * 64 + t] = (red[t] + red[t + 64] + red[t + 128] + red[t + 192]) *
                             (1.0f / (float)HW);
}

// ============ KP: pooled mean over HW (fallback path) ============
__global__ __launch_bounds__(256) void pool_kernel(const ushort_t* __restrict__ h,
                                                   float* __restrict__ pooled) {
    __shared__ float red[4];
    int tid = threadIdx.x;
    const ushort_t* src = h + (size_t)blockIdx.x * HW;
    float s = 0.f;
#pragma unroll 2
    for (int i = tid * 8; i < HW; i += 2048) {
        short8 v = *(const short8*)(src + i);
#pragma unroll
        for (int q = 0; q < 8; ++q) s += h2f((ushort_t)v[q]);
    }
#pragma unroll
    for (int d = 1; d < 64; d <<= 1) s += __shfl_xor(s, d, 64);
    if ((tid & 63) == 0) red[tid >> 6] = s;
    __syncthreads();
    if (tid == 0)
        pooled[blockIdx.x] = (red[0] + red[1] + red[2] + red[3]) * (1.0f / (float)HW);
}

// ============ K3: SE MLP -> cw; per-batch fp16 tap-GEMM weights ============
__global__ void ca_kernel(const float* __restrict__ pooled_g,
                          const float* __restrict__ w1, const float* __restrict__ b1,
                          const float* __restrict__ w2, const float* __restrict__ b2,
                          const float* __restrict__ saw, float* __restrict__ cw,
                          ushort_t* __restrict__ we_bf) {
    __shared__ float pooled[256];
    __shared__ float t1[16];
    int t = threadIdx.x;
    int b = t >> 6, o = t & 63;
    pooled[t] = pooled_g[t];
    __syncthreads();
    if (t < 16) {
        int bb = t >> 2, hh = t & 3;
        float a = b1[hh];
        for (int c = 0; c < 64; ++c) a += pooled[bb * 64 + c] * w1[hh * 64 + c];
        t1[t] = fmaxf(a, 0.f);
    }
    __syncthreads();
    float a = b2[o];
#pragma unroll
    for (int h2 = 0; h2 < 4; ++h2) a += t1[b * 4 + h2] * w2[o * 4 + h2];
    float cwv = 1.f / (1.f + __expf(-a));
    cw[t] = cwv;
    for (int tap = 0; tap < 64; ++tap) {
        float v = (tap < 49) ? cwv * saw[o * 49 + tap] : 0.f;
        we_bf[(b * 64 + tap) * 64 + o] = f2h(v);
    }
}

// ============ K4a: tap GEMM  u[b][t][p] = sum_c we[b][t][c] * h[b][c][p] ============
__global__ __launch_bounds__(256) void tap_gemm_kernel(
    const ushort_t* __restrict__ h, const ushort_t* __restrict__ we_bf,
    ushort_t* __restrict__ u) {
    int tid = threadIdx.x;
    int b = blockIdx.y;
    int p0 = blockIdx.x * 128;
    int wid = tid >> 6, lane = tid & 63, ln = lane & 15, kg = lane >> 4;
    int pA = p0 + wid * 32 + ln, pB = pA + 16;
    const ushort_t* hb = h + (size_t)b * 64 * HW;
    const ushort_t* wt = we_bf + b * 4096;

    f32x4 acc[4][2];
#pragma unroll
    for (int mt = 0; mt < 4; ++mt)
#pragma unroll
        for (int nt = 0; nt < 2; ++nt) acc[mt][nt] = (f32x4){0.f, 0.f, 0.f, 0.f};

#pragma unroll
    for (int ks = 0; ks < 2; ++ks) {
        int ch = ks * 32 + kg * 8;
        short8 fA, fB;
#pragma unroll
        for (int q = 0; q < 8; ++q) {
            fA[q] = (short)hb[(size_t)(ch + q) * HW + pA];
            fB[q] = (short)hb[(size_t)(ch + q) * HW + pB];
        }
        short8 a0 = *(const short8*)(wt + (0 + ln) * 64 + ch);
        short8 a1 = *(const short8*)(wt + (16 + ln) * 64 + ch);
        short8 a2 = *(const short8*)(wt + (32 + ln) * 64 + ch);
        short8 a3 = *(const short8*)(wt + (48 + ln) * 64 + ch);
        acc[0][0] = __builtin_amdgcn_mfma_f32_16x16x32_f16(a0, fA, acc[0][0], 0, 0, 0);
        acc[0][1] = __builtin_amdgcn_mfma_f32_16x16x32_f16(a0, fB, acc[0][1], 0, 0, 0);
        acc[1][0] = __builtin_amdgcn_mfma_f32_16x16x32_f16(a1, fA, acc[1][0], 0, 0, 0);
        acc[1][1] = __builtin_amdgcn_mfma_f32_16x16x32_f16(a1, fB, acc[1][1], 0, 0, 0);
        acc[2][0] = __builtin_amdgcn_mfma_f32_16x16x32_f16(a2, fA, acc[2][0], 0, 0, 0);
        acc[2][1] = __builtin_amdgcn_mfma_f32_16x16x32_f16(a2, fB, acc[2][1], 0, 0, 0);
        acc[3][0] = __builtin_amdgcn_mfma_f32_16x16x32_f16(a3, fA, acc[3][0], 0, 0, 0);
        acc[3][1] = __builtin_amdgcn_mfma_f32_16x16x32_f16(a3, fB, acc[3][1], 0, 0, 0);
    }
#pragma unroll
    for (int mt = 0; mt < 4; ++mt)
#pragma unroll
        for (int r = 0; r < 4; ++r) {
            int m = mt * 16 + kg * 4 + r;
            if (m < 49) {
                ushort_t* up = u + (size_t)(b * 49 + m) * HW;
                up[pA] = f2h(acc[mt][0][r]);
                up[pB] = f2h(acc[mt][1][r]);
            }
        }
}

// ============ K4b: shift-add 49 taps -> sigmoid -> out = h*cw*sw ============
__global__ __launch_bounds__(256) void sa_final_kernel(
    float* __restrict__ out, const ushort_t* __restrict__ h,
    const ushort_t* __restrict__ u,
    const float* __restrict__ cw, const float* __restrict__ sab) {
    __shared__ float cw_l[64];
    int tid = threadIdx.x;
    int b = blockIdx.y;
    int p = blockIdx.x * 256 + tid;
    if (tid < 64) cw_l[tid] = cw[b * 64 + tid];
    __syncthreads();
    int y = p / 192, x = p - y * 192;
    float s = sab[0];
    const ushort_t* ub = u + (size_t)b * 49 * HW;
#pragma unroll
    for (int dy = 0; dy < 7; ++dy)
#pragma unroll
        for (int dx = 0; dx < 7; ++dx) {
            int yy = y + dy - 3, xx = x + dx - 3;
            bool ok = ((unsigned)yy < 192u) && ((unsigned)xx < 192u);
            int ad = ok ? (p + (dy - 3) * 192 + (dx - 3)) : 0;
            float v = h2f(ub[(size_t)(dy * 7 + dx) * HW + ad]);
            s += ok ? v : 0.f;
        }
    float swv = 1.f / (1.f + __expf(-s));
#pragma unroll 8
    for (int c = 0; c < 64; ++c) {
        size_t ix = (size_t)(b * 64 + c) * HW + p;
        out[ix] = h2f(h[ix]) * (cw_l[c] * swv);
    }
}

extern "C" void kernel_launch(void* const* d_in, const int* in_sizes, int n_in,
                              void* d_out, int out_size, void* d_ws, size_t ws_size,
                              hipStream_t stream) {
    const float* x     = (const float*)d_in[0];
    const float* off_w = (const float*)d_in[1];
    const float* off_b = (const float*)d_in[2];
    const float* dw    = (const float*)d_in[3];
    const float* db    = (const float*)d_in[4];
    const float* bn_g  = (const float*)d_in[5];
    const float* bn_b  = (const float*)d_in[6];
    const float* bn_m  = (const float*)d_in[7];
    const float* bn_v  = (const float*)d_in[8];
    const float* ca_w1 = (const float*)d_in[9];
    const float* ca_b1 = (const float*)d_in[10];
    const float* ca_w2 = (const float*)d_in[11];
    const float* ca_b2 = (const float*)d_in[12];
    const float* sa_w  = (const float*)d_in[13];
    const float* sa_b  = (const float*)d_in[14];
    float* out = (float*)d_out;
    float* ws  = (float*)d_ws;

    // ws layout (floats):
    // x_t @0 (4718592); u aliases x_t after deform
    // h16 @4718592 (4718592)
    // w_bf @9437184 (18432); w_off @9455616 (9216; we_bf aliases after deform)
    // scale @9464832  shift @9464896  cw @9464960  pooled @9465216
    // partial [4608][64] @9465472 (294912) -> end 9760384 fl = 39.04 MB (plan A2 only)
    ushort_t* x_t    = (ushort_t*)ws;
    ushort_t* u      = (ushort_t*)ws;
    ushort_t* h16    = (ushort_t*)(ws + 4718592);
    ushort_t* w_bf   = (ushort_t*)(ws + 9437184);
    ushort_t* w_off  = (ushort_t*)(ws + 9455616);
    ushort_t* we_bf  = (ushort_t*)(ws + 9455616);
    float* scale     = ws + 9464832;
    float* shift     = ws + 9464896;
    float* cw        = ws + 9464960;
    float* pooled    = ws + 9465216;
    float* partial   = ws + 9465472;

    const size_t NEED_A2 = 9760384ull * 4ull;   // 39.04 MB

    prep_transpose_kernel<<<576, 256, 0, stream>>>(x, x_t, dw, db, bn_g, bn_b, bn_m,
                                                   bn_v, off_w, w_bf, w_off, scale, shift);
    if (ws_size >= NEED_A2) {
        deform_fused_kernel<true><<<512, 576, 0, stream>>>(x_t, w_off, off_b, w_bf,
                                                           scale, shift, h16, partial);
        reduce_kernel<<<4, 256, 0, stream>>>(partial, pooled);
    } else {
        deform_fused_kernel<false><<<512, 576, 0, stream>>>(x_t, w_off, off_b, w_bf,
                                                            scale, shift, h16, partial);
        pool_kernel<<<256, 256, 0, stream>>>(h16, pooled);
    }
    ca_kernel<<<1, 256, 0, stream>>>(pooled, ca_w1, ca_b1, ca_w2, ca_b2, sa_w, cw, we_bf);
    tap_gemm_kernel<<<dim3(288, 4), 256, 0, stream>>>(h16, we_bf, u);
    sa_final_kernel<<<dim3(144, 4), 256, 0, stream>>>(out, h16, u, cw, sa_b);
}

// Round 21
// 120.776 us; speedup vs baseline: 1.0730x; 1.0730x over previous
//
#include <hip/hip_runtime.h>
#include <hip/hip_fp16.h>

#define H_  192
#define W_  192
#define HW  36864
#define B_  4

typedef __attribute__((ext_vector_type(8))) short short8;
typedef __attribute__((ext_vector_type(4))) float f32x4;
typedef __attribute__((ext_vector_type(4))) unsigned int u32x4;
typedef unsigned short ushort_t;
typedef unsigned int uint_t;

__device__ __forceinline__ ushort_t f2h(float v) {
    __half h = __float2half(v);
    ushort_t s;
    __builtin_memcpy(&s, &h, 2);
    return s;
}
__device__ __forceinline__ float h2f(ushort_t s) {
    __half h;
    __builtin_memcpy(&h, &s, 2);
    return __half2float(h);
}
__device__ __forceinline__ __half2 u2h2(uint_t u) {
    __half2 h;
    __builtin_memcpy(&h, &u, 4);
    return h;
}
__device__ __forceinline__ uint_t h22u(__half2 h) {
    uint_t u;
    __builtin_memcpy(&u, &h, 4);
    return u;
}
__device__ __forceinline__ short8 zero8() {
    u32x4 z = {0u, 0u, 0u, 0u};
    return __builtin_bit_cast(short8, z);
}

// async copy: per-lane global src -> LDS[wave_base + lane*16]
__device__ __forceinline__ void glds16(const ushort_t* src, void* lds_base) {
    __builtin_amdgcn_global_load_lds(
        (const __attribute__((address_space(1))) void*)src,
        (__attribute__((address_space(3))) void*)lds_base, 16, 0, 0);
}

// ============ KT+K0: transpose x -> fp16 NHWC, plus weight prep (merged) ============
__global__ __launch_bounds__(256) void prep_transpose_kernel(
    const float* __restrict__ x, ushort_t* __restrict__ x_t,
    const float* __restrict__ dw, const float* __restrict__ db,
    const float* __restrict__ g, const float* __restrict__ be,
    const float* __restrict__ mu, const float* __restrict__ var,
    const float* __restrict__ ow,
    ushort_t* __restrict__ w_bf, ushort_t* __restrict__ w_off,
    float* __restrict__ scale, float* __restrict__ shift) {
    __shared__ uint_t tlds[256 * 33];
    int tid = threadIdx.x;

    // ---- prep part (blocks 0..215 carry weight work) ----
    int idx = blockIdx.x * 256 + tid;
    if (idx < 36864) {
        int tap = idx >> 12, o = (idx >> 6) & 63, c = idx & 63;
        w_bf[idx] = f2h(dw[(o * 64 + c) * 9 + tap]);
    }
    int idx2 = idx - 36864;
    if (idx2 >= 0 && idx2 < 18432) {
        int tap = idx2 >> 11, o = (idx2 >> 6) & 31, c = idx2 & 63;
        w_off[idx2] = (o < 18) ? f2h(ow[(o * 64 + c) * 9 + tap]) : (ushort_t)0;
    }
    if (idx < 64) {
        float s = g[idx] * rsqrtf(var[idx] + 1e-5f);
        scale[idx] = s;
        shift[idx] = (db[idx] - mu[idx]) * s + be[idx];
    }

    // ---- transpose part ----
    int b = blockIdx.x / 144;
    int p0 = (blockIdx.x % 144) * 256;
    ushort_t* ts = (ushort_t*)tlds;
    for (int c = 0; c < 64; ++c) {
        float v = x[((size_t)(b * 64 + c)) * HW + p0 + tid];
        ts[tid * 66 + c] = f2h(v);
    }
    __syncthreads();
#pragma unroll
    for (int j = 0; j < 8; ++j) {
        int chunk = j * 256 + tid;
        int pl = chunk >> 3, s = chunk & 7;
        int bd = pl * 33 + s * 4;
        u32x4 v = {tlds[bd], tlds[bd + 1], tlds[bd + 2], tlds[bd + 3]};
        ((u32x4*)x_t)[(size_t)(b * HW + p0) * 8 + chunk] = v;
    }
}

// ============ helpers for fused deform ============
__device__ __forceinline__ u32x4 prd(const ushort_t* patch, int q, int slot) {
    return *(const u32x4*)((const char*)patch + q * 128 + ((slot ^ (q & 7)) << 4));
}

__device__ __forceinline__ bool corner_setup2(float ody, float odx,
                                              int ybase, int xbase, int ytop, int xleft,
                                              int* q, int* g, float* w) {
    float py = (float)ybase + ody;
    float px = (float)xbase + odx;
    float fy = floorf(py), fx = floorf(px);
    int y0 = (int)fy, x0 = (int)fx;
    float wy = py - fy, wx = px - fx;
    int y0c = min(max(y0, 0), H_ - 1), y1c = min(max(y0 + 1, 0), H_ - 1);
    int x0c = min(max(x0, 0), W_ - 1), x1c = min(max(x0 + 1, 0), W_ - 1);
    float vy0 = (y0 >= 0 && y0 < H_) ? 1.f : 0.f;
    float vy1 = (y0 + 1 >= 0 && y0 + 1 < H_) ? 1.f : 0.f;
    float vx0 = (x0 >= 0 && x0 < W_) ? 1.f : 0.f;
    float vx1 = (x0 + 1 >= 0 && x0 + 1 < W_) ? 1.f : 0.f;
    w[0] = (1.f - wy) * (1.f - wx) * vy0 * vx0;
    w[1] = (1.f - wy) * wx * vy0 * vx1;
    w[2] = wy * (1.f - wx) * vy1 * vx0;
    w[3] = wy * wx * vy1 * vx1;
    g[0] = (y0c * W_ + x0c) * 64; g[1] = (y0c * W_ + x1c) * 64;
    g[2] = (y1c * W_ + x0c) * 64; g[3] = (y1c * W_ + x1c) * 64;
    int iy0 = y0c - ytop, iy1 = y1c - ytop;
    int ix0 = x0c - xleft, ix1 = x1c - xleft;
    q[0] = iy0 * 56 + ix0; q[1] = iy0 * 56 + ix1;
    q[2] = iy1 * 56 + ix0; q[3] = iy1 * 56 + ix1;
    return ((unsigned)iy0 <= 11u) & ((unsigned)iy1 <= 11u) &
           ((unsigned)ix0 <= 55u) & ((unsigned)ix1 <= 55u);
}

__device__ __forceinline__ short8 interp_f16(const u32x4* buf, const __half2* w2) {
    short8 r;
#pragma unroll
    for (int q = 0; q < 4; ++q) {
        __half2 acc = __hmul2(u2h2(buf[0][q]), w2[0]);
        acc = __hfma2(u2h2(buf[1][q]), w2[1], acc);
        acc = __hfma2(u2h2(buf[2][q]), w2[2], acc);
        acc = __hfma2(u2h2(buf[3][q]), w2[3], acc);
        ((uint_t*)&r)[q] = h22u(acc);
    }
    return r;
}

// ============ K2: fused offset-conv + deformable conv (r19 structure, no fused pool).
// Block = 6 rows x 48 cols = 288 positions, 576 threads (9 waves); patch 12x56 px = 86 KB. ============
__global__ __launch_bounds__(576, 2) void deform_fused_kernel(
    const ushort_t* __restrict__ x_t, const ushort_t* __restrict__ w_off,
    const float* __restrict__ ob, const ushort_t* __restrict__ w_bf,
    const float* __restrict__ scale_g, const float* __restrict__ shift_g,
    ushort_t* __restrict__ h16) {
    __shared__ __align__(16) ushort_t patch[672 * 64];   // 86016 B

    int tid = threadIdx.x;
    int lane = tid & 63, w = tid >> 6;
    int tile = (blockIdx.x & 7) * 64 + (blockIdx.x >> 3);   // XCD-bijective
    int b = tile / 128;
    int rem = tile % 128;
    int y0 = (rem >> 2) * 6;
    int x0 = (rem & 3) * 48;
    int ytop = y0 - 3, xleft = x0 - 4;

    int ln = lane & 15, kg = lane >> 4;
    int locA = w * 32 + ln, locB = locA + 16;
    int rowA = locA / 48, colA = locA - rowA * 48;
    int rowB = locB / 48, colB = locB - rowB * 48;
    int yA = y0 + rowA, xA = x0 + colA;
    int yB = y0 + rowB, xB = x0 + colB;
    const ushort_t* xt_b = x_t + (size_t)b * (HW * 64);

    // ---- stage halo patch ----
    {
        char* pbase = (char*)patch;
#pragma unroll
        for (int t = 0; t < 10; ++t) {
            if (t * 576 + w * 64 < 5376) {
                int g = t * 576 + tid;
                int q = g >> 3, sp = g & 7;
                int i = q / 56, j = q - i * 56;
                int pr = min(max(ytop + i, 0), H_ - 1);
                int pc = min(max(xleft + j, 0), W_ - 1);
                int s = sp ^ (q & 7);
                glds16(xt_b + (pr * W_ + pc) * 64 + s * 8,
                       pbase + (size_t)(t * 576 + w * 64) * 16);
            }
        }
    }
    asm volatile("s_waitcnt vmcnt(0)" ::: "memory");
    __syncthreads();

    // ---- phase 0: offset conv ----
    f32x4 ao[2][2];
#pragma unroll
    for (int i = 0; i < 2; ++i)
#pragma unroll
        for (int j = 0; j < 2; ++j) ao[i][j] = (f32x4){0.f, 0.f, 0.f, 0.f};

    for (int tap = 0; tap < 9; ++tap) {
        int ti = tap / 3 - 1, tj = tap % 3 - 1;
        bool vA = ((unsigned)(yA + ti) < (unsigned)H_) && ((unsigned)(xA + tj) < (unsigned)W_);
        bool vB = ((unsigned)(yB + ti) < (unsigned)H_) && ((unsigned)(xB + tj) < (unsigned)W_);
        int qA = (rowA + 3 + ti) * 56 + (colA + 4 + tj);
        int qB = (rowB + 3 + ti) * 56 + (colB + 4 + tj);
        const ushort_t* wt = w_off + tap * 2048;
#pragma unroll
        for (int ks = 0; ks < 2; ++ks) {
            int ch = ks * 32 + kg * 8;
            int slot = kg + ks * 4;
            short8 a0 = *(const short8*)(wt + ln * 64 + ch);
            short8 a1 = *(const short8*)(wt + (16 + ln) * 64 + ch);
            short8 bA = vA ? __builtin_bit_cast(short8, prd(patch, qA, slot)) : zero8();
            short8 bB = vB ? __builtin_bit_cast(short8, prd(patch, qB, slot)) : zero8();
            ao[0][0] = __builtin_amdgcn_mfma_f32_16x16x32_f16(a0, bA, ao[0][0], 0, 0, 0);
            ao[0][1] = __builtin_amdgcn_mfma_f32_16x16x32_f16(a0, bB, ao[0][1], 0, 0, 0);
            ao[1][0] = __builtin_amdgcn_mfma_f32_16x16x32_f16(a1, bA, ao[1][0], 0, 0, 0);
            ao[1][1] = __builtin_amdgcn_mfma_f32_16x16x32_f16(a1, bB, ao[1][1], 0, 0, 0);
        }
    }

    // ---- redistribute offsets via intra-wave shuffles ----
    float offA[18], offB[18];
#pragma unroll
    for (int m = 0; m < 18; ++m) {
        int src = (((m >> 2) & 3) << 4) | ln;
        float bias = ob[m];
        offA[m] = __shfl(ao[m >> 4][0][m & 3], src, 64) + bias;
        offB[m] = __shfl(ao[m >> 4][1][m & 3], src, 64) + bias;
    }

    // ---- main: deformable conv ----
    f32x4 acc[4][2];
#pragma unroll
    for (int mt = 0; mt < 4; ++mt)
#pragma unroll
        for (int nt = 0; nt < 2; ++nt) acc[mt][nt] = (f32x4){0.f, 0.f, 0.f, 0.f};

#pragma unroll
    for (int tap = 0; tap < 9; ++tap) {
        int ti = tap / 3 - 1, tj = tap % 3 - 1;
        int qA[4], qB[4], gA[4], gB[4];
        float wA[4], wB[4];
        bool inA = corner_setup2(offA[2 * tap], offA[2 * tap + 1],
                                 yA + ti, xA + tj, ytop, xleft, qA, gA, wA);
        bool inB = corner_setup2(offB[2 * tap], offB[2 * tap + 1],
                                 yB + ti, xB + tj, ytop, xleft, qB, gB, wB);
        __half2 wA2[4], wB2[4];
#pragma unroll
        for (int c = 0; c < 4; ++c) {
            wA2[c] = __float2half2_rn(wA[c]);
            wB2[c] = __float2half2_rn(wB[c]);
        }
        const ushort_t* wt = w_bf + tap * 4096;
#pragma unroll
        for (int ks = 0; ks < 2; ++ks) {
            int ch = ks * 32 + kg * 8;
            int slot = kg + ks * 4;
            u32x4 cA[4], cB[4];
            if (__builtin_expect(inA, 1)) {
#pragma unroll
                for (int c = 0; c < 4; ++c) cA[c] = prd(patch, qA[c], slot);
            } else {
#pragma unroll
                for (int c = 0; c < 4; ++c) cA[c] = *(const u32x4*)(xt_b + gA[c] + ch);
            }
            if (__builtin_expect(inB, 1)) {
#pragma unroll
                for (int c = 0; c < 4; ++c) cB[c] = prd(patch, qB[c], slot);
            } else {
#pragma unroll
                for (int c = 0; c < 4; ++c) cB[c] = *(const u32x4*)(xt_b + gB[c] + ch);
            }
            short8 fA = interp_f16(cA, wA2);
            short8 fB = interp_f16(cB, wB2);
            short8 a0 = *(const short8*)(wt + (0 + ln) * 64 + ch);
            short8 a1 = *(const short8*)(wt + (16 + ln) * 64 + ch);
            short8 a2 = *(const short8*)(wt + (32 + ln) * 64 + ch);
            short8 a3 = *(const short8*)(wt + (48 + ln) * 64 + ch);
            acc[0][0] = __builtin_amdgcn_mfma_f32_16x16x32_f16(a0, fA, acc[0][0], 0, 0, 0);
            acc[0][1] = __builtin_amdgcn_mfma_f32_16x16x32_f16(a0, fB, acc[0][1], 0, 0, 0);
            acc[1][0] = __builtin_amdgcn_mfma_f32_16x16x32_f16(a1, fA, acc[1][0], 0, 0, 0);
            acc[1][1] = __builtin_amdgcn_mfma_f32_16x16x32_f16(a1, fB, acc[1][1], 0, 0, 0);
            acc[2][0] = __builtin_amdgcn_mfma_f32_16x16x32_f16(a2, fA, acc[2][0], 0, 0, 0);
            acc[2][1] = __builtin_amdgcn_mfma_f32_16x16x32_f16(a2, fB, acc[2][1], 0, 0, 0);
            acc[3][0] = __builtin_amdgcn_mfma_f32_16x16x32_f16(a3, fA, acc[3][0], 0, 0, 0);
            acc[3][1] = __builtin_amdgcn_mfma_f32_16x16x32_f16(a3, fB, acc[3][1], 0, 0, 0);
        }
    }

    // ---- epilogue: BN affine + fp16 store ----
    int pixA = yA * W_ + xA;
    int pixB = yB * W_ + xB;
#pragma unroll
    for (int mt = 0; mt < 4; ++mt) {
#pragma unroll
        for (int r = 0; r < 4; ++r) {
            int m = mt * 16 + kg * 4 + r;
            float sc = scale_g[m], sh = shift_g[m];
            size_t obase = (size_t)(b * 64 + m) * HW;
            h16[obase + pixA] = f2h(acc[mt][0][r] * sc + sh);
            h16[obase + pixB] = f2h(acc[mt][1][r] * sc + sh);
        }
    }
}

// ============ KP: pooled mean over HW ============
__global__ __launch_bounds__(256) void pool_kernel(const ushort_t* __restrict__ h,
                                                   float* __restrict__ pooled) {
    __shared__ float red[4];
    int tid = threadIdx.x;
    const ushort_t* src = h + (size_t)blockIdx.x * HW;
    float s = 0.f;
#pragma unroll 2
    for (int i = tid * 8; i < HW; i += 2048) {
        short8 v = *(const short8*)(src + i);
#pragma unroll
        for (int q = 0; q < 8; ++q) s += h2f((ushort_t)v[q]);
    }
#pragma unroll
    for (int d = 1; d < 64; d <<= 1) s += __shfl_xor(s, d, 64);
    if ((tid & 63) == 0) red[tid >> 6] = s;
    __syncthreads();
    if (tid == 0)
        pooled[blockIdx.x] = (red[0] + red[1] + red[2] + red[3]) * (1.0f / (float)HW);
}

// ============ K3: SE MLP -> cw; per-batch fp16 tap-GEMM weights ============
__global__ void ca_kernel(const float* __restrict__ pooled_g,
                          const float* __restrict__ w1, const float* __restrict__ b1,
                          const float* __restrict__ w2, const float* __restrict__ b2,
                          const float* __restrict__ saw, float* __restrict__ cw,
                          ushort_t* __restrict__ we_bf) {
    __shared__ float pooled[256];
    __shared__ float t1[16];
    int t = threadIdx.x;
    int b = t >> 6, o = t & 63;
    pooled[t] = pooled_g[t];
    __syncthreads();
    if (t < 16) {
        int bb = t >> 2, hh = t & 3;
        float a = b1[hh];
        for (int c = 0; c < 64; ++c) a += pooled[bb * 64 + c] * w1[hh * 64 + c];
        t1[t] = fmaxf(a, 0.f);
    }
    __syncthreads();
    float a = b2[o];
#pragma unroll
    for (int h2 = 0; h2 < 4; ++h2) a += t1[b * 4 + h2] * w2[o * 4 + h2];
    float cwv = 1.f / (1.f + __expf(-a));
    cw[t] = cwv;
    for (int tap = 0; tap < 64; ++tap) {
        float v = (tap < 49) ? cwv * saw[o * 49 + tap] : 0.f;
        we_bf[(b * 64 + tap) * 64 + o] = f2h(v);
    }
}

// ============ K4a: tap GEMM  u[b][t][p] = sum_c we[b][t][c] * h[b][c][p] ============
__global__ __launch_bounds__(256) void tap_gemm_kernel(
    const ushort_t* __restrict__ h, const ushort_t* __restrict__ we_bf,
    ushort_t* __restrict__ u) {
    int tid = threadIdx.x;
    int b = blockIdx.y;
    int p0 = blockIdx.x * 128;
    int wid = tid >> 6, lane = tid & 63, ln = lane & 15, kg = lane >> 4;
    int pA = p0 + wid * 32 + ln, pB = pA + 16;
    const ushort_t* hb = h + (size_t)b * 64 * HW;
    const ushort_t* wt = we_bf + b * 4096;

    f32x4 acc[4][2];
#pragma unroll
    for (int mt = 0; mt < 4; ++mt)
#pragma unroll
        for (int nt = 0; nt < 2; ++nt) acc[mt][nt] = (f32x4){0.f, 0.f, 0.f, 0.f};

#pragma unroll
    for (int ks = 0; ks < 2; ++ks) {
        int ch = ks * 32 + kg * 8;
        short8 fA, fB;
#pragma unroll
        for (int q = 0; q < 8; ++q) {
            fA[q] = (short)hb[(size_t)(ch + q) * HW + pA];
            fB[q] = (short)hb[(size_t)(ch + q) * HW + pB];
        }
        short8 a0 = *(const short8*)(wt + (0 + ln) * 64 + ch);
        short8 a1 = *(const short8*)(wt + (16 + ln) * 64 + ch);
        short8 a2 = *(const short8*)(wt + (32 + ln) * 64 + ch);
        short8 a3 = *(const short8*)(wt + (48 + ln) * 64 + ch);
        acc[0][0] = __builtin_amdgcn_mfma_f32_16x16x32_f16(a0, fA, acc[0][0], 0, 0, 0);
        acc[0][1] = __builtin_amdgcn_mfma_f32_16x16x32_f16(a0, fB, acc[0][1], 0, 0, 0);
        acc[1][0] = __builtin_amdgcn_mfma_f32_16x16x32_f16(a1, fA, acc[1][0], 0, 0, 0);
        acc[1][1] = __builtin_amdgcn_mfma_f32_16x16x32_f16(a1, fB, acc[1][1], 0, 0, 0);
        acc[2][0] = __builtin_amdgcn_mfma_f32_16x16x32_f16(a2, fA, acc[2][0], 0, 0, 0);
        acc[2][1] = __builtin_amdgcn_mfma_f32_16x16x32_f16(a2, fB, acc[2][1], 0, 0, 0);
        acc[3][0] = __builtin_amdgcn_mfma_f32_16x16x32_f16(a3, fA, acc[3][0], 0, 0, 0);
        acc[3][1] = __builtin_amdgcn_mfma_f32_16x16x32_f16(a3, fB, acc[3][1], 0, 0, 0);
    }
#pragma unroll
    for (int mt = 0; mt < 4; ++mt)
#pragma unroll
        for (int r = 0; r < 4; ++r) {
            int m = mt * 16 + kg * 4 + r;
            if (m < 49) {
                ushort_t* up = u + (size_t)(b * 49 + m) * HW;
                up[pA] = f2h(acc[mt][0][r]);
                up[pB] = f2h(acc[mt][1][r]);
            }
        }
}

// ============ K4b: shift-add 49 taps -> sigmoid -> out = h*cw*sw ============
__global__ __launch_bounds__(256) void sa_final_kernel(
    float* __restrict__ out, const ushort_t* __restrict__ h,
    const ushort_t* __restrict__ u,
    const float* __restrict__ cw, const float* __restrict__ sab) {
    __shared__ float cw_l[64];
    int tid = threadIdx.x;
    int b = blockIdx.y;
    int p = blockIdx.x * 256 + tid;
    if (tid < 64) cw_l[tid] = cw[b * 64 + tid];
    __syncthreads();
    int y = p / 192, x = p - y * 192;
    float s = sab[0];
    const ushort_t* ub = u + (size_t)b * 49 * HW;
#pragma unroll
    for (int dy = 0; dy < 7; ++dy)
#pragma unroll
        for (int dx = 0; dx < 7; ++dx) {
            int yy = y + dy - 3, xx = x + dx - 3;
            bool ok = ((unsigned)yy < 192u) && ((unsigned)xx < 192u);
            int ad = ok ? (p + (dy - 3) * 192 + (dx - 3)) : 0;
            float v = h2f(ub[(size_t)(dy * 7 + dx) * HW + ad]);
            s += ok ? v : 0.f;
        }
    float swv = 1.f / (1.f + __expf(-s));
#pragma unroll 8
    for (int c = 0; c < 64; ++c) {
        size_t ix = (size_t)(b * 64 + c) * HW + p;
        out[ix] = h2f(h[ix]) * (cw_l[c] * swv);
    }
}

extern "C" void kernel_launch(void* const* d_in, const int* in_sizes, int n_in,
                              void* d_out, int out_size, void* d_ws, size_t ws_size,
                              hipStream_t stream) {
    const float* x     = (const float*)d_in[0];
    const float* off_w = (const float*)d_in[1];
    const float* off_b = (const float*)d_in[2];
    const float* dw    = (const float*)d_in[3];
    const float* db    = (const float*)d_in[4];
    const float* bn_g  = (const float*)d_in[5];
    const float* bn_b  = (const float*)d_in[6];
    const float* bn_m  = (const float*)d_in[7];
    const float* bn_v  = (const float*)d_in[8];
    const float* ca_w1 = (const float*)d_in[9];
    const float* ca_b1 = (const float*)d_in[10];
    const float* ca_w2 = (const float*)d_in[11];
    const float* ca_b2 = (const float*)d_in[12];
    const float* sa_w  = (const float*)d_in[13];
    const float* sa_b  = (const float*)d_in[14];
    float* out = (float*)d_out;
    float* ws  = (float*)d_ws;

    // ws layout (floats) — 37.9 MB (proven available in r19):
    // x_t @0 (4718592); u aliases x_t after deform
    // h16 @4718592 (4718592)
    // w_bf @9437184 (18432); w_off @9455616 (9216; we_bf aliases after deform)
    // scale @9464832  shift @9464896  cw @9464960  pooled @9465216
    ushort_t* x_t    = (ushort_t*)ws;
    ushort_t* u      = (ushort_t*)ws;
    ushort_t* h16    = (ushort_t*)(ws + 4718592);
    ushort_t* w_bf   = (ushort_t*)(ws + 9437184);
    ushort_t* w_off  = (ushort_t*)(ws + 9455616);
    ushort_t* we_bf  = (ushort_t*)(ws + 9455616);
    float* scale     = ws + 9464832;
    float* shift     = ws + 9464896;
    float* cw        = ws + 9464960;
    float* pooled    = ws + 9465216;

    prep_transpose_kernel<<<576, 256, 0, stream>>>(x, x_t, dw, db, bn_g, bn_b, bn_m,
                                                   bn_v, off_w, w_bf, w_off, scale, shift);
    deform_fused_kernel<<<512, 576, 0, stream>>>(x_t, w_off, off_b, w_bf,
                                                 scale, shift, h16);
    pool_kernel<<<256, 256, 0, stream>>>(h16, pooled);
    ca_kernel<<<1, 256, 0, stream>>>(pooled, ca_w1, ca_b1, ca_w2, ca_b2, sa_w, cw, we_bf);
    tap_gemm_kernel<<<dim3(288, 4), 256, 0, stream>>>(h16, we_bf, u);
    sa_final_kernel<<<dim3(144, 4), 256, 0, stream>>>(out, h16, u, cw, sa_b);
}